// Round 2
// baseline (528.953 us; speedup 1.0000x reference)
//
#include <hip/hip_runtime.h>

// BroadcastTC: per (b,c) pair p (p = b*C+c, NPAIR = 8192*128):
//   a = T1[p, 0:27] viewed as [x][y][k], b = T2[p, 0:27] viewed as [k][u][v]
//   out1[p, x,y,u,v] = sum_k a[x,y,k] b[k,u,v] / sqrt(3)     (81 floats)
//   out2[p, x,u]     = sum_{k,l} a[x,k,l] b[k,l,u] / 3        (9 floats)
//   out3[p]          = sum_j a[j] b[j] / sqrt(27)             (1 float)
// Memory-bound: ~608 MB total traffic -> ~97us roofline @ 6.3 TB/s.
// Strategy: thread = pair. LDS is purely a coalescing buffer:
//   - inputs staged via contiguous float4 loads,
//   - out1 stored in 4 pair-groups of 64: owning wave computes 81 values ->
//     LDS, then all waves store one contiguous 16B-aligned 20736B block
//     (float4), i.e. exact full-line writes, no partial-line RMW,
//   - out2 staged and stored as one contiguous float4 block.

#define TPB 256
#define PPB 256

constexpr int  NPAIR    = 8192 * 128;                 // 1,048,576
constexpr long OUT2_OFF = (long)NPAIR * 81;           // 84,934,656
constexpr long OUT3_OFF = OUT2_OFF + (long)NPAIR * 9; // 94,371,840

__global__ __launch_bounds__(TPB)
void btc_kernel(const float* __restrict__ T1, const float* __restrict__ T2,
                float* __restrict__ out)
{
    // 27648 B: reused for T1 stage, T2 stage, out1 groups, out2 block.
    __shared__ __align__(16) float lds[PPB * 27];

    const int  tid      = threadIdx.x;
    const long pairBase = (long)blockIdx.x * PPB;

    // ---- stage T1 (contiguous float4 loads) -> registers ----
    {
        const float4* g = reinterpret_cast<const float4*>(T1 + pairBase * 27);
        float4*       l = reinterpret_cast<float4*>(lds);
        #pragma unroll
        for (int i = 0; i < 7; ++i) {
            int idx = tid + i * TPB;
            if (idx < (PPB * 27) / 4) l[idx] = g[idx];
        }
    }
    __syncthreads();
    float a[27];
    #pragma unroll
    for (int j = 0; j < 27; ++j) a[j] = lds[tid * 27 + j];  // stride 27: 2-way bank alias = free
    __syncthreads();

    // ---- stage T2 -> registers ----
    {
        const float4* g = reinterpret_cast<const float4*>(T2 + pairBase * 27);
        float4*       l = reinterpret_cast<float4*>(lds);
        #pragma unroll
        for (int i = 0; i < 7; ++i) {
            int idx = tid + i * TPB;
            if (idx < (PPB * 27) / 4) l[idx] = g[idx];
        }
    }
    __syncthreads();
    float b[27];
    #pragma unroll
    for (int j = 0; j < 27; ++j) b[j] = lds[tid * 27 + j];
    __syncthreads();

    const float n1 = 0.57735026918962576f;  // 1/sqrt(3)
    const float n2 = 0.33333333333333333f;  // 1/3
    const float n3 = 0.19245008972987526f;  // 1/sqrt(27)

    // ---- out1: 4 groups of 64 pairs; wave g computes -> LDS, all store ----
    #pragma unroll 1
    for (int g = 0; g < 4; ++g) {
        if ((tid >> 6) == g) {              // wave-uniform branch, no divergence
            const int lp = tid & 63;
            #pragma unroll
            for (int x = 0; x < 3; ++x)
                #pragma unroll
                for (int y = 0; y < 3; ++y)
                    #pragma unroll
                    for (int u = 0; u < 3; ++u)
                        #pragma unroll
                        for (int v = 0; v < 3; ++v) {
                            float s = a[x*9 + y*3 + 0] * b[ 0 + u*3 + v]
                                    + a[x*9 + y*3 + 1] * b[ 9 + u*3 + v]
                                    + a[x*9 + y*3 + 2] * b[18 + u*3 + v];
                            // stride 81 across lanes: (81l+j)%32 covers all
                            // banks exactly 2x -> conflict-free for wave64
                            lds[lp * 81 + x*27 + y*9 + u*3 + v] = s * n1;
                        }
        }
        __syncthreads();
        // contiguous 64 pairs * 81 floats = 5184 floats = 1296 float4 (16B-aligned)
        {
            const float4* ls = reinterpret_cast<const float4*>(lds);
            float4*       go = reinterpret_cast<float4*>(out + (pairBase + g * 64) * 81);
            #pragma unroll
            for (int k = 0; k < 6; ++k) {
                int idx = tid + k * TPB;
                if (idx < 1296) go[idx] = ls[idx];
            }
        }
        __syncthreads();
    }

    // ---- out2: 9 floats/pair -> LDS, one contiguous float4 block store ----
    #pragma unroll
    for (int x = 0; x < 3; ++x) {
        #pragma unroll
        for (int u = 0; u < 3; ++u) {
            float s = 0.f;
            #pragma unroll
            for (int k = 0; k < 3; ++k)
                #pragma unroll
                for (int l = 0; l < 3; ++l)
                    s += a[x*9 + k*3 + l] * b[k*9 + l*3 + u];
            lds[tid * 9 + x*3 + u] = s * n2;   // stride 9: 2-way alias, free
        }
    }
    __syncthreads();
    {
        // 256 pairs * 9 floats = 2304 floats = 576 float4 (offsets all 16B-aligned)
        const float4* ls = reinterpret_cast<const float4*>(lds);
        float4*       go = reinterpret_cast<float4*>(out + OUT2_OFF + pairBase * 9);
        #pragma unroll
        for (int k = 0; k < 3; ++k) {
            int idx = tid + k * TPB;
            if (idx < 576) go[idx] = ls[idx];
        }
    }

    // ---- out3: 1 float/pair, naturally coalesced ----
    float s3 = 0.f;
    #pragma unroll
    for (int j = 0; j < 27; ++j) s3 += a[j] * b[j];
    out[OUT3_OFF + pairBase + tid] = s3 * n3;
}

extern "C" void kernel_launch(void* const* d_in, const int* in_sizes, int n_in,
                              void* d_out, int out_size, void* d_ws, size_t ws_size,
                              hipStream_t stream)
{
    const float* T1  = (const float*)d_in[0];
    const float* T2  = (const float*)d_in[1];
    float*       out = (float*)d_out;

    dim3 grid(NPAIR / PPB);
    dim3 block(TPB);
    hipLaunchKernelGGL(btc_kernel, grid, block, 0, stream, T1, T2, out);
}

// Round 3
// 511.333 us; speedup vs baseline: 1.0345x; 1.0345x over previous
//
#include <hip/hip_runtime.h>

// BroadcastTC, wave-autonomous version. Per (b,c) pair p (NPAIR = 8192*128):
//   a = T1[p,0:27] as [x][y][k], b = T2[p,0:27] as [k][u][v]
//   out1[p,x,y,u,v] = sum_k a[x,y,k] b[k,u,v] / sqrt(3)   (81 floats)
//   out2[p,x,u]     = sum_{k,l} a[x,k,l] b[k,l,u] / 3      (9 floats)
//   out3[p]         = sum_j a[j] b[j] / sqrt(27)           (1 float)
//
// Structure: TPB=64 -> ONE wave per workgroup, ZERO __syncthreads. Each wave
// owns 32 pairs; lanes l and l+32 both compute pair l&31 (redundant compute
// is ~free: total VALU ~11us vs ~97us mandatory HBM). LDS (10368B/block ->
// ~15 blocks/CU) is purely a coalescing buffer; every global access is
// contiguous float4/dword. Rationale: previous kernel had 13 __syncthreads,
// each = s_waitcnt vmcnt(0) lgkmcnt(0) + s_barrier -> drains all global
// stores at every phase boundary. Here waves stream fully independently.

#define TPB 64

constexpr int  NPAIR    = 8192 * 128;                 // 1,048,576
constexpr int  PPW      = 32;                         // pairs per wave
constexpr long OUT2_OFF = (long)NPAIR * 81;           // 84,934,656
constexpr long OUT3_OFF = OUT2_OFF + (long)NPAIR * 9; // 94,371,840

__global__ __launch_bounds__(TPB)
void btc_kernel(const float* __restrict__ T1, const float* __restrict__ T2,
                float* __restrict__ out)
{
    // 2592 floats = 10368 B, reused across phases (same-wave DS ops execute
    // in order; compiler preserves DS order via alias analysis):
    //   phase 1: T1 stage at [0..864), T2 stage at [864..1728)
    //   phase 2: out1 tile  at [0..2592)   (32 pairs x 81)
    //   phase 3: out2 tile  at [0..288)    (32 pairs x 9)
    __shared__ __align__(16) float buf[PPW * 81];

    const int  lane     = threadIdx.x;      // 0..63
    const int  h        = lane >> 5;        // half: 0 or 1
    const int  p        = lane & 31;        // local pair owned by this lane
    const long pairBase = (long)blockIdx.x * PPW;

    // ---- stage T1+T2 (contiguous float4 global loads -> LDS) ----
    // Each input tile: 32 pairs * 27 floats = 864 floats = 216 float4.
    {
        const float4* g1 = reinterpret_cast<const float4*>(T1 + pairBase * 27);
        const float4* g2 = reinterpret_cast<const float4*>(T2 + pairBase * 27);
        float4*       lb = reinterpret_cast<float4*>(buf);
        #pragma unroll
        for (int r = 0; r < 3; ++r) lb[r * 64 + lane]       = g1[r * 64 + lane];
        if (lane < 24)              lb[192 + lane]          = g1[192 + lane];
        #pragma unroll
        for (int r = 0; r < 3; ++r) lb[216 + r * 64 + lane] = g2[r * 64 + lane];
        if (lane < 24)              lb[216 + 192 + lane]    = g2[192 + lane];
    }

    // ---- per-lane register pull (2 lanes/addr broadcast; stride 27,
    //      gcd(27,32)=1 -> all 32 banks hit once -> conflict-free) ----
    float a[27], b[27];
    #pragma unroll
    for (int t = 0; t < 27; ++t) a[t] = buf[p * 27 + t];
    #pragma unroll
    for (int t = 0; t < 27; ++t) b[t] = buf[864 + p * 27 + t];

    const float n1 = 0.57735026918962576f;  // 1/sqrt(3)
    const float n2 = 0.33333333333333333f;  // 1/3
    const float n3 = 0.19245008972987526f;  // 1/sqrt(27)

    // ---- out1: both halves compute all 81; h=0 writes j<=40, h=1 writes
    //   j>=41 (half-exec ds_write; stride 81 dwords: gcd(81,32)=1 -> the 32
    //   active lanes hit all 32 banks exactly once -> conflict-free) ----
    #pragma unroll
    for (int x = 0; x < 3; ++x)
        #pragma unroll
        for (int y = 0; y < 3; ++y)
            #pragma unroll
            for (int u = 0; u < 3; ++u)
                #pragma unroll
                for (int v = 0; v < 3; ++v) {
                    const int j = x * 27 + y * 9 + u * 3 + v;
                    float s = a[x*9 + y*3 + 0] * b[ 0 + u*3 + v]
                            + a[x*9 + y*3 + 1] * b[ 9 + u*3 + v]
                            + a[x*9 + y*3 + 2] * b[18 + u*3 + v];
                    if ((j > 40) == (h == 1))       // j<=40 -> h0, j>=41 -> h1
                        buf[p * 81 + j] = s * n1;
                }

    // ---- out1 store: 2592 floats = 648 float4, fully contiguous ----
    {
        const float4* lb = reinterpret_cast<const float4*>(buf);
        float4*       go = reinterpret_cast<float4*>(out + pairBase * 81);
        #pragma unroll
        for (int r = 0; r < 10; ++r) go[r * 64 + lane] = lb[r * 64 + lane];
        if (lane < 8)                go[640 + lane]    = lb[640 + lane];
    }

    // ---- out2: all lanes compute, h=0 lanes write (stride 9: conflict-free)
    #pragma unroll
    for (int x = 0; x < 3; ++x)
        #pragma unroll
        for (int u = 0; u < 3; ++u) {
            float s = 0.f;
            #pragma unroll
            for (int k = 0; k < 3; ++k)
                #pragma unroll
                for (int l = 0; l < 3; ++l)
                    s += a[x*9 + k*3 + l] * b[k*9 + l*3 + u];
            if (h == 0) buf[p * 9 + x * 3 + u] = s * n2;
        }

    // ---- out2 store: 288 floats = 72 float4 contiguous ----
    {
        const float4* lb = reinterpret_cast<const float4*>(buf);
        float4*       go = reinterpret_cast<float4*>(out + OUT2_OFF + pairBase * 9);
        go[lane] = lb[lane];                       // 64 float4
        if (lane < 8) go[64 + lane] = lb[64 + lane];
    }

    // ---- out3: direct half-exec dword store (32 consecutive = 128B line) --
    float s3 = 0.f;
    #pragma unroll
    for (int t = 0; t < 27; ++t) s3 += a[t] * b[t];
    if (h == 0) out[OUT3_OFF + pairBase + p] = s3 * n3;
}

extern "C" void kernel_launch(void* const* d_in, const int* in_sizes, int n_in,
                              void* d_out, int out_size, void* d_ws, size_t ws_size,
                              hipStream_t stream)
{
    const float* T1  = (const float*)d_in[0];
    const float* T2  = (const float*)d_in[1];
    float*       out = (float*)d_out;

    dim3 grid(NPAIR / PPW);   // 32768 one-wave workgroups
    dim3 block(TPB);
    hipLaunchKernelGGL(btc_kernel, grid, block, 0, stream, T1, T2, out);
}